// Round 4
// baseline (757.436 us; speedup 1.0000x reference)
//
#include <hip/hip_runtime.h>

#define C_DIM 128
#define EPS 1e-5f
#define NBIN 784   // buckets of 64 nodes; bin = dst >> 6 (covers N <= 50176)
#define SBLK 8192  // edges per hist/scatter block

typedef __attribute__((ext_vector_type(8))) short short8;
typedef __attribute__((ext_vector_type(4))) float f32x4;
typedef __attribute__((ext_vector_type(2))) float f32x2;

__device__ __forceinline__ unsigned bf16rn(float f) {
    unsigned u = __float_as_uint(f);
    return (u + 0x7fffu + ((u >> 16) & 1u)) >> 16;
}
__device__ __forceinline__ unsigned pack_bf16(float lo, float hi) {
    return bf16rn(lo) | (bf16rn(hi) << 16);
}
__device__ __forceinline__ float blo(unsigned u) { return __uint_as_float(u << 16); }
__device__ __forceinline__ float bhi(unsigned u) { return __uint_as_float(u & 0xffff0000u); }

// exclusive scan of buf[0..n) by ONE full wave (all 64 lanes must enter).
// If dump, also writes gb[i]=exclusive prefix, gc[i]=original value.
__device__ __forceinline__ void wave_scan_excl(unsigned* buf, int n, int lane,
                                               unsigned* gb, unsigned* gc, bool dump) {
    const int CH = (NBIN + 63) / 64;  // 13
    unsigned v[CH];
    unsigned s = 0;
    int c0 = lane * CH;
#pragma unroll
    for (int k = 0; k < CH; k++) {
        int idx = c0 + k;
        v[k] = (idx < n) ? buf[idx] : 0u;
        s += v[k];
    }
    unsigned inc = s;
#pragma unroll
    for (int off = 1; off < 64; off <<= 1) {
        unsigned tmp = __shfl_up(inc, off);
        if (lane >= off) inc += tmp;
    }
    unsigned run = inc - s;  // exclusive prefix of this lane's chunk
#pragma unroll
    for (int k = 0; k < CH; k++) {
        int idx = c0 + k;
        if (idx < n) {
            if (dump) { gb[idx] = run; gc[idx] = v[k]; }
            buf[idx] = run;
            run += v[k];
        }
    }
}

// ---------------- P0: coarse histogram (dst>>6) | W transposes ----------------
__global__ __launch_bounds__(256) void p0(const float* __restrict__ W,
                                          const float* __restrict__ Wfc,
                                          unsigned short* __restrict__ WhT,
                                          unsigned short* __restrict__ WlT,
                                          unsigned short* __restrict__ WT,
                                          const int* __restrict__ edst,
                                          unsigned* __restrict__ H, int e, int nsb) {
    __shared__ unsigned lh[NBIN];
    int b = blockIdx.x, t = threadIdx.x;
    if (b < nsb) {
        for (int k = t; k < NBIN; k += 256) lh[k] = 0u;
        __syncthreads();
        int e0 = b * SBLK;
        int lim = e - e0; if (lim > SBLK) lim = SBLK;
        for (int k = t; k < lim; k += 256) {
            int d = edst[e0 + k];
            atomicAdd(&lh[d >> 6], 1u);
        }
        __syncthreads();
        for (int k = t; k < NBIN; k += 256) H[(size_t)k * nsb + b] = lh[k];
    } else {
        int gid = (b - nsb) * 256 + t;
        int stride = ((int)gridDim.x - nsb) * 256;
        for (int i = gid; i < 128 * 128; i += stride) {
            int c = i >> 7, k = i & 127;
            float v = W[k * 128 + c];
            unsigned hi = bf16rn(v);
            WhT[c * 128 + k] = (unsigned short)hi;
            WlT[c * 128 + k] = (unsigned short)bf16rn(v - __uint_as_float(hi << 16));
        }
        for (int i = gid; i < 48 * 128; i += stride) {
            int nc = i >> 7, k = i & 127;
            WT[nc * 128 + k] = (unsigned short)((nc < 40) ? bf16rn(Wfc[k * 40 + nc]) : 0u);
        }
    }
}

// ---------------- F1: bucket scatter (no global atomics) | gemm1 MFMA ----------------
// rec = (bin<<22) | (dstlow<<16) | src
__global__ __launch_bounds__(256, 3) void f1(const float* __restrict__ x,
                                             const unsigned short* __restrict__ WhT,
                                             const unsigned short* __restrict__ WlT,
                                             unsigned short* __restrict__ hbs,
                                             const int* __restrict__ esrc,
                                             const int* __restrict__ edst,
                                             const unsigned* __restrict__ H,
                                             unsigned* __restrict__ recs,
                                             unsigned* __restrict__ bstart,
                                             unsigned* __restrict__ bcnt,
                                             int n, int e, int nsb) {
    __shared__ unsigned bufA[NBIN];  // totals -> base -> local rank cursors
    __shared__ unsigned bufB[NBIN];  // my-block exclusive offset -> global chunk start
    __shared__ unsigned bufC[NBIN];  // local hist -> local sorted start
    __shared__ unsigned sbuf[SBLK];
    int b = blockIdx.x, t = threadIdx.x;

    if (b < nsb) {
        int e0 = b * SBLK;
        int myE = e - e0; if (myE > SBLK) myE = SBLK;
        for (int k = t; k < NBIN; k += 256) bufC[k] = 0u;
        __syncthreads();
        // local hist
        for (int k = t; k < myE; k += 256) {
            int d = edst[e0 + k];
            atomicAdd(&bufC[d >> 6], 1u);
        }
        // column sums over H: total per bin + my exclusive offset
        for (int bin = t; bin < NBIN; bin += 256) {
            const unsigned* row = H + (size_t)bin * nsb;
            unsigned my = 0, tot = 0;
            for (int sb = 0; sb < nsb; sb++) {
                unsigned hv = row[sb];
                tot += hv;
                if (sb < b) my += hv;
            }
            bufA[bin] = tot;
            bufB[bin] = my;
        }
        __syncthreads();
        int wv = t >> 6, lane = t & 63;
        if (wv == 0) wave_scan_excl(bufA, NBIN, lane, bstart, bcnt, b == 0);
        else if (wv == 1) wave_scan_excl(bufC, NBIN, lane, 0, 0, false);
        __syncthreads();
        for (int bin = t; bin < NBIN; bin += 256) {
            bufB[bin] += bufA[bin];  // global chunk start for this block
            bufA[bin] = 0u;          // reuse as local rank cursor
        }
        __syncthreads();
        // rank + LDS sort
        for (int k = t; k < myE; k += 256) {
            int d = edst[e0 + k];
            int s = esrc[e0 + k];
            int bin = d >> 6;
            unsigned lr = atomicAdd(&bufA[bin], 1u);
            sbuf[bufC[bin] + lr] =
                ((unsigned)bin << 22) | ((unsigned)(d & 63) << 16) | (unsigned)s;
        }
        __syncthreads();
        // write bin-grouped runs (lane-adjacent slots -> mostly-contiguous gpos)
        for (int j = t; j < myE; j += 256) {
            unsigned rec = sbuf[j];
            unsigned bin = rec >> 22;
            unsigned gpos = bufB[bin] + (unsigned)j - bufC[bin];
            recs[gpos] = rec;
        }
    } else {
        // ---- gemm1: h = x @ W_conv via 16x16x32 bf16 MFMA, hi/lo split ----
        int r0 = (b - nsb) * 128;
        int wid = t >> 6, lane = t & 63;
        int mrow = lane & 15, quad = lane >> 4;
        int rb = r0 + wid * 32;

        f32x4 acc[2][8];
#pragma unroll
        for (int m = 0; m < 2; m++)
#pragma unroll
            for (int nn = 0; nn < 8; nn++) acc[m][nn] = (f32x4){0.f, 0.f, 0.f, 0.f};

#pragma unroll
        for (int ks = 0; ks < 4; ks++) {
            short8 Ah[2], Al[2];
#pragma unroll
            for (int m = 0; m < 2; m++) {
                int r = rb + m * 16 + mrow;
                if (r >= n) r = n - 1;
                const float* xp = &x[(long)r * C_DIM + ks * 32 + quad * 8];
                float4 va = *(const float4*)xp;
                float4 vb = *(const float4*)(xp + 4);
                float xv[8] = {va.x, va.y, va.z, va.w, vb.x, vb.y, vb.z, vb.w};
#pragma unroll
                for (int e8 = 0; e8 < 8; e8++) {
                    unsigned hi = bf16rn(xv[e8]);
                    Ah[m][e8] = (short)hi;
                    Al[m][e8] = (short)bf16rn(xv[e8] - __uint_as_float(hi << 16));
                }
            }
#pragma unroll
            for (int nn = 0; nn < 8; nn++) {
                int wof = (nn * 16 + mrow) * 128 + ks * 32 + quad * 8;
                short8 Bh = *(const short8*)&WhT[wof];
                short8 Bl = *(const short8*)&WlT[wof];
#pragma unroll
                for (int m = 0; m < 2; m++) {
                    acc[m][nn] = __builtin_amdgcn_mfma_f32_16x16x32_bf16(Ah[m], Bh, acc[m][nn], 0, 0, 0);
                    acc[m][nn] = __builtin_amdgcn_mfma_f32_16x16x32_bf16(Al[m], Bh, acc[m][nn], 0, 0, 0);
                    acc[m][nn] = __builtin_amdgcn_mfma_f32_16x16x32_bf16(Ah[m], Bl, acc[m][nn], 0, 0, 0);
                }
            }
        }
#pragma unroll
        for (int m = 0; m < 2; m++)
#pragma unroll
            for (int nn = 0; nn < 8; nn++) {
                int c = nn * 16 + mrow;
#pragma unroll
                for (int reg = 0; reg < 4; reg++) {
                    int r = rb + m * 16 + quad * 4 + reg;
                    if (r < n) hbs[(long)r * 128 + c] = (unsigned short)bf16rn(acc[m][nn][reg]);
                }
            }
    }
}

// ---------------- A1: per-node degree -> dinv (replaces all cnt gathers) ----------------
__global__ __launch_bounds__(256) void a1(const unsigned* __restrict__ recs,
                                          const unsigned* __restrict__ bstart,
                                          const unsigned* __restrict__ bcnt,
                                          float* __restrict__ dinvp) {
    __shared__ unsigned dh[64];
    int bin = blockIdx.x, t = threadIdx.x;
    if (t < 64) dh[t] = 0u;
    __syncthreads();
    unsigned s0 = bstart[bin], cn = bcnt[bin];
    for (unsigned k = t; k < cn; k += 256) {
        unsigned rec = recs[s0 + k];
        atomicAdd(&dh[(rec >> 16) & 63u], 1u);
    }
    __syncthreads();
    if (t < 64) dinvp[bin * 64 + t] = rsqrtf((float)dh[t] + 1.0f);
}

// ---------------- MEGA: LDS-accumulate agg + bias + relu*x + LN + residual + gemm2 ----
// One block per bucket (64 nodes). acc[row][ai] with ai(col)= col/2 + (col&1)*64
// so lane L owns cols (2L, 2L+1) at ai = L and 64+L  (bank-conflict-free ds_add).
__global__ __launch_bounds__(256, 3) void mega(const unsigned* __restrict__ hbu,
                                               const float* __restrict__ x,
                                               const unsigned* __restrict__ recs,
                                               const float* __restrict__ dinvp,
                                               const unsigned* __restrict__ bstart,
                                               const unsigned* __restrict__ bcnt,
                                               const unsigned short* __restrict__ WT,
                                               const float* __restrict__ bconv,
                                               const float* __restrict__ gamma,
                                               const float* __restrict__ beta,
                                               const float* __restrict__ bfc,
                                               float* __restrict__ out, int n) {
    __shared__ float accs[64 * 128];
    __shared__ unsigned zl[64 * 70];  // stride 70 u32: odd-ish bank rotation, 8B aligned
    __shared__ float dvo[64];
    int bin = blockIdx.x, t = threadIdx.x;
    int wv = t >> 6, L = t & 63;

    for (int k = t; k < 2048; k += 256) ((f32x4*)accs)[k] = (f32x4){0.f, 0.f, 0.f, 0.f};
    if (t < 64) dvo[t] = dinvp[bin * 64 + t];
    __syncthreads();

    unsigned start = bstart[bin], cnt = bcnt[bin];
    int nb = ((int)cnt + 63) >> 6;
    for (int bb = wv; bb < nb; bb += 4) {  // wave-uniform trip count per wave
        int k0g = bb << 6;
        bool val = (unsigned)(k0g + L) < cnt;
        unsigned rec = val ? recs[start + k0g + L] : 0u;
        float wgt = val ? dinvp[rec & 0xFFFFu] : 0.f;
#pragma unroll 1
        for (int k0 = 0; k0 < 64; k0 += 8) {
            unsigned rc[8]; float wk[8]; unsigned hv[8];
#pragma unroll
            for (int q = 0; q < 8; q++) {
                rc[q] = __shfl(rec, k0 + q);
                wk[q] = __shfl(wgt, k0 + q);
            }
#pragma unroll
            for (int q = 0; q < 8; q++)
                hv[q] = hbu[(size_t)(rc[q] & 0xFFFFu) * 64 + L];
#pragma unroll
            for (int q = 0; q < 8; q++) {
                int row = (int)((rc[q] >> 16) & 63u);
                __hip_atomic_fetch_add(&accs[row * 128 + L], wk[q] * blo(hv[q]),
                                       __ATOMIC_RELAXED, __HIP_MEMORY_SCOPE_WORKGROUP);
                __hip_atomic_fetch_add(&accs[row * 128 + 64 + L], wk[q] * bhi(hv[q]),
                                       __ATOMIC_RELAXED, __HIP_MEMORY_SCOPE_WORKGROUP);
            }
        }
    }
    __syncthreads();

    // epilogue: wave wv owns rows [wv*16, wv*16+16); whole wave works one row at a time
#pragma unroll
    for (int r16 = 0; r16 < 16; r16++) {
        int row = wv * 16 + r16;
        int node = bin * 64 + row;
        bool vn = node < n;
        float p0 = accs[row * 128 + L];
        float p1 = accs[row * 128 + 64 + L];
        unsigned hv = 0u;
        f32x2 xv = (f32x2){0.f, 0.f};
        if (vn) {
            hv = hbu[(size_t)node * 64 + L];
            xv = ((const f32x2*)x)[(size_t)node * 64 + L];
        }
        float dv = dvo[row];
        p0 = dv * p0 + dv * dv * blo(hv);
        p1 = dv * p1 + dv * dv * bhi(hv);
        f32x2 bc = ((const f32x2*)bconv)[L];
        float a0 = fmaxf(p0 + bc.x, 0.f) * xv.x;
        float a1 = fmaxf(p1 + bc.y, 0.f) * xv.y;
        float s = a0 + a1;
#pragma unroll
        for (int off = 1; off < 64; off <<= 1) s += __shfl_xor(s, off);
        float mu = s * (1.0f / 128.0f);
        float d0 = a0 - mu, d1 = a1 - mu;
        float v = d0 * d0 + d1 * d1;
#pragma unroll
        for (int off = 1; off < 64; off <<= 1) v += __shfl_xor(v, off);
        float inv = rsqrtf(v * (1.0f / 128.0f) + EPS);
        f32x2 gm = ((const f32x2*)gamma)[L];
        f32x2 bt = ((const f32x2*)beta)[L];
        float o0 = d0 * inv * gm.x + bt.x + xv.x;
        float o1 = d1 * inv * gm.y + bt.y + xv.y;
        zl[row * 70 + L] = pack_bf16(o0, o1);
    }
    __syncthreads();

    // fused gemm2: wave wv does rows [wv*16,+16) x WT(48x128) -> out cols 0..39
    int mrow = L & 15, quad = L >> 4;
    f32x4 a2[3];
#pragma unroll
    for (int nt = 0; nt < 3; nt++) a2[nt] = (f32x4){0.f, 0.f, 0.f, 0.f};
#pragma unroll
    for (int ks = 0; ks < 4; ks++) {
        int zi = (wv * 16 + mrow) * 70 + ks * 16 + quad * 4;
        union { unsigned u[4]; short8 s; } au;
        au.u[0] = zl[zi + 0];
        au.u[1] = zl[zi + 1];
        au.u[2] = zl[zi + 2];
        au.u[3] = zl[zi + 3];
        short8 B[3];
#pragma unroll
        for (int nt = 0; nt < 3; nt++)
            B[nt] = *(const short8*)&WT[(nt * 16 + mrow) * 128 + ks * 32 + quad * 8];
#pragma unroll
        for (int nt = 0; nt < 3; nt++)
            a2[nt] = __builtin_amdgcn_mfma_f32_16x16x32_bf16(au.s, B[nt], a2[nt], 0, 0, 0);
    }
#pragma unroll
    for (int nt = 0; nt < 3; nt++) {
        int c = nt * 16 + mrow;
        if (c < 40) {
            float bias = bfc[c];
#pragma unroll
            for (int reg = 0; reg < 4; reg++) {
                int r = bin * 64 + wv * 16 + quad * 4 + reg;
                if (r < n) out[(size_t)r * 40 + c] = a2[nt][reg] + bias;
            }
        }
    }
}

extern "C" void kernel_launch(void* const* d_in, const int* in_sizes, int n_in,
                              void* d_out, int out_size, void* d_ws, size_t ws_size,
                              hipStream_t stream) {
    const float* x     = (const float*)d_in[0];
    const int*   ei    = (const int*)d_in[1];
    const float* Wc    = (const float*)d_in[2];
    const float* bc    = (const float*)d_in[3];
    const float* gamma = (const float*)d_in[4];
    const float* beta  = (const float*)d_in[5];
    const float* Wfc   = (const float*)d_in[6];
    const float* bfc   = (const float*)d_in[7];
    float* out = (float*)d_out;

    int N = in_sizes[0] / C_DIM;
    int E = in_sizes[1] / 2;
    const int* esrc = ei;
    const int* edst = ei + E;
    int nsb = (E + SBLK - 1) / SBLK;  // 79 for E=640000

    char* p = (char*)d_ws;
    auto carve = [&](size_t bytes) {
        void* q = (void*)p;
        p += (bytes + 255) & ~(size_t)255;
        return q;
    };
    unsigned* hb        = (unsigned*)carve((size_t)N * 64 * 4);        // h bf16 pairs
    unsigned short* WT  = (unsigned short*)carve(48 * 128 * 2);        // W_fc^T bf16
    unsigned short* WhT = (unsigned short*)carve(128 * 128 * 2);       // W_conv^T hi
    unsigned short* WlT = (unsigned short*)carve(128 * 128 * 2);       // W_conv^T lo
    unsigned* H         = (unsigned*)carve((size_t)NBIN * nsb * 4);    // coarse hist
    unsigned* recs      = (unsigned*)carve((size_t)E * 4);             // sorted records
    unsigned* bstart    = (unsigned*)carve((size_t)NBIN * 4);
    unsigned* bcnt      = (unsigned*)carve((size_t)NBIN * 4);
    float* dinvp        = (float*)carve((size_t)NBIN * 64 * 4);        // padded dinv

    int g1 = (N + 127) / 128;

    p0<<<nsb + 64, 256, 0, stream>>>(Wc, Wfc, WhT, WlT, WT, edst, H, E, nsb);
    f1<<<nsb + g1, 256, 0, stream>>>(x, WhT, WlT, (unsigned short*)hb, esrc, edst, H,
                                     recs, bstart, bcnt, N, E, nsb);
    a1<<<NBIN, 256, 0, stream>>>(recs, bstart, bcnt, dinvp);
    mega<<<NBIN, 256, 0, stream>>>(hb, x, recs, dinvp, bstart, bcnt, WT, bc, gamma,
                                   beta, bfc, out, N);
}

// Round 5
// 184.997 us; speedup vs baseline: 4.0943x; 4.0943x over previous
//
#include <hip/hip_runtime.h>

#define C_DIM 128
#define EPS 1e-5f
#define CSTRIDE 16  // ints per counter slot = 64B: ONE counter per cache line (anti-false-sharing)

typedef __attribute__((ext_vector_type(8))) short short8;
typedef __attribute__((ext_vector_type(4))) float f32x4;

__device__ __forceinline__ unsigned bf16rn(float f) {
    unsigned u = __float_as_uint(f);
    return (u + 0x7fffu + ((u >> 16) & 1u)) >> 16;
}
__device__ __forceinline__ unsigned pack_bf16(float lo, float hi) {
    return bf16rn(lo) | (bf16rn(hi) << 16);
}
__device__ __forceinline__ float blo(unsigned u) { return __uint_as_float(u << 16); }
__device__ __forceinline__ float bhi(unsigned u) { return __uint_as_float(u & 0xffff0000u); }

// ---------------- prep0: zero padded counters (float4) + W transposes ----------------
__global__ void prep0(const float* __restrict__ W, const float* __restrict__ Wfc,
                      unsigned short* __restrict__ WhT, unsigned short* __restrict__ WlT,
                      unsigned short* __restrict__ WT,
                      float4* __restrict__ cz, int czn) {
    int gid = blockIdx.x * blockDim.x + threadIdx.x;
    int stride = gridDim.x * blockDim.x;
    for (int t = gid; t < 128 * 128; t += stride) {
        int c = t >> 7, k = t & 127;
        float v = W[k * 128 + c];
        unsigned hi = bf16rn(v);
        float fh = __uint_as_float(hi << 16);
        WhT[c * 128 + k] = (unsigned short)hi;
        WlT[c * 128 + k] = (unsigned short)bf16rn(v - fh);
    }
    for (int t = gid; t < 48 * 128; t += stride) {
        int nc = t >> 7, k = t & 127;
        WT[nc * 128 + k] = (unsigned short)((nc < 40) ? bf16rn(Wfc[k * 40 + nc]) : 0u);
    }
    float4 z = make_float4(0.f, 0.f, 0.f, 0.f);
    for (int t = gid; t < czn; t += stride) cz[t] = z;
}

// ---------------- FAT: gemm1 split-bf16 MFMA | edge scatter (padded counters) -------
// (verbatim from round 3 — the 62us atomic service-rate wall is attacked next round)
__global__ __launch_bounds__(256, 4) void fat(const float* __restrict__ x,
                                              const unsigned short* __restrict__ WhT,
                                              const unsigned short* __restrict__ WlT,
                                              unsigned short* __restrict__ hbs,
                                              const int* __restrict__ esrc,
                                              const int* __restrict__ edst,
                                              int* __restrict__ cntA,
                                              int* __restrict__ cntB,
                                              unsigned short* __restrict__ bsrcu,
                                              int n, int e, int g1) {
    int b = blockIdx.x;
    int t = threadIdx.x;

    if (b < g1) {
        // ---- gemm1: h = x @ W_conv via 16x16x32 bf16 MFMA, hi/lo split, no LDS ----
        int r0 = b * 128;
        int wid = t >> 6, lane = t & 63;
        int mrow = lane & 15, quad = lane >> 4;
        int rb = r0 + wid * 32;  // wave owns 32 rows x 128 cols

        f32x4 acc[2][8];
#pragma unroll
        for (int m = 0; m < 2; m++)
#pragma unroll
            for (int nn = 0; nn < 8; nn++) acc[m][nn] = (f32x4){0.f, 0.f, 0.f, 0.f};

#pragma unroll
        for (int ks = 0; ks < 4; ks++) {
            short8 Ah[2], Al[2];
#pragma unroll
            for (int m = 0; m < 2; m++) {
                int r = rb + m * 16 + mrow;
                if (r >= n) r = n - 1;  // clamp loads; stores guarded
                const float* xp = &x[(long)r * C_DIM + ks * 32 + quad * 8];
                float4 va = *(const float4*)xp;
                float4 vb = *(const float4*)(xp + 4);
                float xv[8] = {va.x, va.y, va.z, va.w, vb.x, vb.y, vb.z, vb.w};
#pragma unroll
                for (int e8 = 0; e8 < 8; e8++) {
                    unsigned hi = bf16rn(xv[e8]);
                    Ah[m][e8] = (short)hi;
                    Al[m][e8] = (short)bf16rn(xv[e8] - __uint_as_float(hi << 16));
                }
            }
#pragma unroll
            for (int nn = 0; nn < 8; nn++) {
                int wof = (nn * 16 + mrow) * 128 + ks * 32 + quad * 8;
                short8 Bh = *(const short8*)&WhT[wof];
                short8 Bl = *(const short8*)&WlT[wof];
#pragma unroll
                for (int m = 0; m < 2; m++) {
                    acc[m][nn] = __builtin_amdgcn_mfma_f32_16x16x32_bf16(Ah[m], Bh, acc[m][nn], 0, 0, 0);
                    acc[m][nn] = __builtin_amdgcn_mfma_f32_16x16x32_bf16(Al[m], Bh, acc[m][nn], 0, 0, 0);
                    acc[m][nn] = __builtin_amdgcn_mfma_f32_16x16x32_bf16(Ah[m], Bl, acc[m][nn], 0, 0, 0);
                }
            }
        }
        // C/D layout (same as verified gemm2): row = quad*4 + reg, col = nn*16 + mrow
#pragma unroll
        for (int m = 0; m < 2; m++)
#pragma unroll
            for (int nn = 0; nn < 8; nn++) {
                int c = nn * 16 + mrow;
#pragma unroll
                for (int reg = 0; reg < 4; reg++) {
                    int r = rb + m * 16 + quad * 4 + reg;
                    if (r < n) hbs[(long)r * 128 + c] = (unsigned short)bf16rn(acc[m][nn][reg]);
                }
            }
    } else {
        // ---- scatter: 4 edges/thread; quarters 0-1 -> cntA/front, 2-3 -> cntB/back
        int sb = b - g1;
        int q = (e + 3) >> 2;
        int i0 = sb * 256 + t;
        int i1 = i0 + q, i2 = i0 + 2 * q, i3 = i0 + 3 * q;
        bool v0 = i0 < e, v1 = i1 < e, v2 = i2 < e, v3 = i3 < e;
        int d0 = v0 ? edst[i0] : 0, s0 = v0 ? esrc[i0] : 0;
        int d1 = v1 ? edst[i1] : 0, s1 = v1 ? esrc[i1] : 0;
        int d2 = v2 ? edst[i2] : 0, s2 = v2 ? esrc[i2] : 0;
        int d3 = v3 ? edst[i3] : 0, s3 = v3 ? esrc[i3] : 0;
        int p0 = v0 ? atomicAdd(&cntA[(long)d0 * CSTRIDE], 1) : 64;
        int p1 = v1 ? atomicAdd(&cntA[(long)d1 * CSTRIDE], 1) : 64;
        int p2 = v2 ? atomicAdd(&cntB[(long)d2 * CSTRIDE], 1) : 64;
        int p3 = v3 ? atomicAdd(&cntB[(long)d3 * CSTRIDE], 1) : 64;
        if (p0 < 64) bsrcu[(long)d0 * 64 + p0] = (unsigned short)s0;
        if (p1 < 64) bsrcu[(long)d1 * 64 + p1] = (unsigned short)s1;
        if (p2 < 64) bsrcu[(long)d2 * 64 + 63 - p2] = (unsigned short)s2;
        if (p3 < 64) bsrcu[(long)d3 * 64 + 63 - p3] = (unsigned short)s3;
    }
}

// ---------------- d0: hb2[s] = bf16( dinv[s] * h[s] ) ------------------------------
// Pre-scaling by the source-side norm makes the aggregate a pure unweighted sum:
// agg[i] = di * ( sum_nbr hb2[s] + hb2[i] )  — no per-neighbor counter gathers at all.
__global__ __launch_bounds__(256) void d0(const unsigned* __restrict__ hb,
                                          const int* __restrict__ cntA,
                                          const int* __restrict__ cntB,
                                          unsigned* __restrict__ hb2, int n) {
    int gid = blockIdx.x * 256 + threadIdx.x;  // one uint4 (8 bf16 values) per thread
    if (gid >= n * 16) return;
    int row = gid >> 4;
    float di = rsqrtf((float)(cntA[(long)row * CSTRIDE] + cntB[(long)row * CSTRIDE]) + 1.0f);
    uint4 u = ((const uint4*)hb)[gid];
    uint4 o;
    o.x = pack_bf16(di * blo(u.x), di * bhi(u.x));
    o.y = pack_bf16(di * blo(u.y), di * bhi(u.y));
    o.z = pack_bf16(di * blo(u.z), di * bhi(u.z));
    o.w = pack_bf16(di * blo(u.w), di * bhi(u.w));
    ((uint4*)hb2)[gid] = o;
}

// ---------------- fused aggregate + bias + relu*x + LN + residual --------------
// One wave per node (50K waves — parallelism is what hides gather latency; the
// round-4 bucket design with 3136 waves was 12x slower). Slot table = src ids
// only (weights pre-folded into hb2 by d0). Gather loop WAVE-UNIFORM (round-1
// lesson: __shfl from an inactive lane returns 0).
__global__ __launch_bounds__(256) void aggregate(const unsigned* __restrict__ hb2,
                                                 const float* __restrict__ x,
                                                 const int* __restrict__ cntA,
                                                 const int* __restrict__ cntB,
                                                 const unsigned short* __restrict__ bsrcu,
                                                 const float* __restrict__ bconv,
                                                 const float* __restrict__ gamma,
                                                 const float* __restrict__ beta,
                                                 unsigned* __restrict__ zb, int n) {
    int wid = (blockIdx.x * blockDim.x + threadIdx.x) >> 6;
    if (wid >= n) return;  // wave-uniform
    int lane = threadIdx.x & 63;
    int sub = lane & 15, grp = lane >> 4;
    int i = wid;

    // hoist independent loads
    uint4 us = *(const uint4*)(hb2 + (long)i * 64 + sub * 4);
    float4 xa = *(const float4*)&x[(long)i * C_DIM + sub * 8];
    float4 xb = *(const float4*)&x[(long)i * C_DIM + sub * 8 + 4];
    int sraw = (int)bsrcu[(long)i * 64 + lane];

    int dA = cntA[(long)i * CSTRIDE], dB = cntB[(long)i * CSTRIDE];
    float di = rsqrtf((float)(dA + dB) + 1.0f);
    if (dA > 64) dA = 64;
    if (dB > 64 - dA) dB = 64 - dA;
    int tot = dA + dB;
    int shift = 64 - tot;  // maps compact index t in [dA,tot) to back region

    int s_all = ((lane < dA) | (lane >= 64 - dB)) ? sraw : 0;

    float wself = (grp == 0) ? 1.f : 0.f;  // self term = hb2[i] (di applied after reduce)
    float acc[8];
    acc[0] = wself * blo(us.x); acc[1] = wself * bhi(us.x);
    acc[2] = wself * blo(us.y); acc[3] = wself * bhi(us.y);
    acc[4] = wself * blo(us.z); acc[5] = wself * bhi(us.z);
    acc[6] = wself * blo(us.w); acc[7] = wself * bhi(us.w);

    int nIt = (tot + 15) >> 4;  // UNIFORM trip count; 16 slots (4 per grp) per iter
    for (int it = 0; it < nIt; ++it) {
        int tb = grp + it * 16;
        int ss[4];
        float ww[4];
#pragma unroll
        for (int qq = 0; qq < 4; qq++) {
            int tq = tb + qq * 4;
            int slq = ((tq < dA) ? tq : tq + shift) & 63;
            int sq = __shfl(s_all, slq);  // full-exec bpermute
            float wq = 1.f;
            if (tq >= tot) { wq = 0.f; sq = i; }  // predicate AFTER shuffle (self row = L1 hit)
            ss[qq] = sq;
            ww[qq] = wq;
        }
        uint4 u[4];
#pragma unroll
        for (int qq = 0; qq < 4; qq++) u[qq] = *(const uint4*)(hb2 + (long)ss[qq] * 64 + sub * 4);
#pragma unroll
        for (int qq = 0; qq < 4; qq++) {
            float w = ww[qq];
            acc[0] += w * blo(u[qq].x); acc[1] += w * bhi(u[qq].x);
            acc[2] += w * blo(u[qq].y); acc[3] += w * bhi(u[qq].y);
            acc[4] += w * blo(u[qq].z); acc[5] += w * bhi(u[qq].z);
            acc[6] += w * blo(u[qq].w); acc[7] += w * bhi(u[qq].w);
        }
    }

#pragma unroll
    for (int j = 0; j < 8; j++) {
        acc[j] += __shfl_xor(acc[j], 16);
        acc[j] += __shfl_xor(acc[j], 32);
    }

    float4 bca = *(const float4*)&bconv[sub * 8];
    float4 bcb = *(const float4*)&bconv[sub * 8 + 4];
    float a[8], xv[8];
    xv[0] = xa.x; xv[1] = xa.y; xv[2] = xa.z; xv[3] = xa.w;
    xv[4] = xb.x; xv[5] = xb.y; xv[6] = xb.z; xv[7] = xb.w;
    float bc[8] = {bca.x, bca.y, bca.z, bca.w, bcb.x, bcb.y, bcb.z, bcb.w};
#pragma unroll
    for (int j = 0; j < 8; j++) a[j] = fmaxf(acc[j] * di + bc[j], 0.f) * xv[j];

    float s = a[0] + a[1] + a[2] + a[3] + a[4] + a[5] + a[6] + a[7];
#pragma unroll
    for (int off = 1; off < 16; off <<= 1) s += __shfl_xor(s, off);
    float mu = s * (1.0f / 128.0f);
    float d[8], v = 0.f;
#pragma unroll
    for (int j = 0; j < 8; j++) { d[j] = a[j] - mu; v += d[j] * d[j]; }
#pragma unroll
    for (int off = 1; off < 16; off <<= 1) v += __shfl_xor(v, off);
    float inv = rsqrtf(v * (1.0f / 128.0f) + EPS);

    if (grp == 0) {
        float4 ga = *(const float4*)&gamma[sub * 8];
        float4 gb = *(const float4*)&gamma[sub * 8 + 4];
        float4 ba = *(const float4*)&beta[sub * 8];
        float4 bb = *(const float4*)&beta[sub * 8 + 4];
        float g[8] = {ga.x, ga.y, ga.z, ga.w, gb.x, gb.y, gb.z, gb.w};
        float be[8] = {ba.x, ba.y, ba.z, ba.w, bb.x, bb.y, bb.z, bb.w};
        float o[8];
#pragma unroll
        for (int j = 0; j < 8; j++) o[j] = d[j] * inv * g[j] + be[j] + xv[j];
        uint4 p;
        p.x = pack_bf16(o[0], o[1]);
        p.y = pack_bf16(o[2], o[3]);
        p.z = pack_bf16(o[4], o[5]);
        p.w = pack_bf16(o[6], o[7]);
        *(uint4*)(zb + (long)i * 64 + sub * 4) = p;
    }
}

// ---------------- GEMM2: out = z @ W_fc + b_fc via bf16 MFMA, no LDS ----------------
// One wave per 16 rows: grid = N/64 blocks (782, was 196) -> 3128 waves. The old
// 4-rows-of-64 layout left the GPU at 0.76 blocks/CU — latency-starved at ~50us.
__global__ __launch_bounds__(256) void gemm2(const unsigned short* __restrict__ zb,
                                             const unsigned short* __restrict__ WT,
                                             const float* __restrict__ bfc,
                                             float* __restrict__ out, int n) {
    int t = threadIdx.x;
    int w = t >> 6, lane = t & 63;
    int r0 = blockIdx.x * 64 + w * 16;
    if (r0 >= n) return;  // wave-uniform
    int mrow = lane & 15;
    int quad = lane >> 4;
    f32x4 acc[3];
#pragma unroll
    for (int nt = 0; nt < 3; nt++) acc[nt] = (f32x4){0.f, 0.f, 0.f, 0.f};
#pragma unroll
    for (int ks = 0; ks < 4; ks++) {
        int r = r0 + mrow;
        if (r >= n) r = n - 1;  // clamp (stores are guarded)
        short8 A = *(const short8*)&zb[(long)r * 128 + ks * 32 + quad * 8];
        short8 B[3];
#pragma unroll
        for (int nt = 0; nt < 3; nt++)
            B[nt] = *(const short8*)&WT[(nt * 16 + mrow) * 128 + ks * 32 + quad * 8];
#pragma unroll
        for (int nt = 0; nt < 3; nt++)
            acc[nt] = __builtin_amdgcn_mfma_f32_16x16x32_bf16(A, B[nt], acc[nt], 0, 0, 0);
    }
#pragma unroll
    for (int nt = 0; nt < 3; nt++) {
        int c = nt * 16 + mrow;
        if (c < 40) {
            float bias = bfc[c];
#pragma unroll
            for (int reg = 0; reg < 4; reg++) {
                int r = r0 + quad * 4 + reg;
                if (r < n) out[(long)r * 40 + c] = acc[nt][reg] + bias;
            }
        }
    }
}

extern "C" void kernel_launch(void* const* d_in, const int* in_sizes, int n_in,
                              void* d_out, int out_size, void* d_ws, size_t ws_size,
                              hipStream_t stream) {
    const float* x     = (const float*)d_in[0];
    const int*   ei    = (const int*)d_in[1];
    const float* Wc    = (const float*)d_in[2];
    const float* bc    = (const float*)d_in[3];
    const float* gamma = (const float*)d_in[4];
    const float* beta  = (const float*)d_in[5];
    const float* Wfc   = (const float*)d_in[6];
    const float* bfc   = (const float*)d_in[7];
    float* out = (float*)d_out;

    int N = in_sizes[0] / C_DIM;
    int E = in_sizes[1] / 2;
    const int* esrc = ei;
    const int* edst = ei + E;

    char* p = (char*)d_ws;
    auto carve = [&](size_t bytes) {
        void* q = (void*)p;
        p += (bytes + 255) & ~(size_t)255;
        return q;
    };
    unsigned* hb        = (unsigned*)carve((size_t)N * 64 * 4);   // h bf16 pairs (reused as zb)
    unsigned* hb2       = (unsigned*)carve((size_t)N * 64 * 4);   // dinv-scaled h bf16 pairs
    unsigned short* WT  = (unsigned short*)carve(48 * 128 * 2);   // W_fc^T bf16
    unsigned short* WhT = (unsigned short*)carve(128 * 128 * 2);  // W_conv^T hi bf16
    unsigned short* WlT = (unsigned short*)carve(128 * 128 * 2);  // W_conv^T lo bf16
    int* cntA           = (int*)carve((size_t)N * CSTRIDE * 4);   // padded: 1 counter / 64B line
    int* cntB           = (int*)carve((size_t)N * CSTRIDE * 4);
    unsigned short* bsrcu = (unsigned short*)carve((size_t)N * 64 * 2);  // padded CSR (ushort)

    unsigned* zb = hb;  // alias: hb is dead after d0

    int czn = (N * CSTRIDE * 2) / 4;  // float4 count (cntA+cntB contiguous)
    prep0<<<256, 256, 0, stream>>>(Wc, Wfc, WhT, WlT, WT, (float4*)cntA, czn);

    int g1 = (N + 127) / 128;                  // gemm1 blocks (128 rows each)
    int nscat = (((E + 3) >> 2) + 255) / 256;  // 4 edges/thread
    fat<<<g1 + nscat, 256, 0, stream>>>(x, WhT, WlT, (unsigned short*)hb, esrc, edst,
                                        cntA, cntB, bsrcu, N, E, g1);

    d0<<<(N * 16 + 255) / 256, 256, 0, stream>>>(hb, cntA, cntB, hb2, N);

    aggregate<<<((size_t)N * 64 + 255) / 256, 256, 0, stream>>>(
        hb2, x, cntA, cntB, bsrcu, bc, gamma, beta, zb, N);

    gemm2<<<(N + 63) / 64, 256, 0, stream>>>((const unsigned short*)zb, WT, bfc, out, N);
}

// Round 7
// 171.688 us; speedup vs baseline: 4.4117x; 1.0775x over previous
//
#include <hip/hip_runtime.h>

#define C_DIM 128
#define EPS 1e-5f
#define NBIN 784   // bins of 64 nodes (capacity; covers N <= 50176)
#define SBLK 2048  // edges per hist/sort block -> 313 blocks for E=640000

typedef __attribute__((ext_vector_type(8))) short short8;
typedef __attribute__((ext_vector_type(4))) float f32x4;

__device__ __forceinline__ unsigned bf16rn(float f) {
    unsigned u = __float_as_uint(f);
    return (u + 0x7fffu + ((u >> 16) & 1u)) >> 16;
}
__device__ __forceinline__ unsigned pack_bf16(float lo, float hi) {
    return bf16rn(lo) | (bf16rn(hi) << 16);
}
__device__ __forceinline__ float blo(unsigned u) { return __uint_as_float(u << 16); }
__device__ __forceinline__ float bhi(unsigned u) { return __uint_as_float(u & 0xffff0000u); }

// exclusive scan of LDS buf[0..NBIN) by ONE full wave (all 64 lanes enter).
__device__ __forceinline__ void wave_scan_excl_lds(unsigned* buf, int lane) {
    const int CH = (NBIN + 63) / 64;  // 13
    unsigned v[CH];
    unsigned s = 0;
    int c0 = lane * CH;
#pragma unroll
    for (int k = 0; k < CH; k++) {
        int idx = c0 + k;
        v[k] = (idx < NBIN) ? buf[idx] : 0u;
        s += v[k];
    }
    unsigned inc = s;
#pragma unroll
    for (int off = 1; off < 64; off <<= 1) {
        unsigned tmp = __shfl_up(inc, off);
        if (lane >= off) inc += tmp;
    }
    unsigned run = inc - s;
#pragma unroll
    for (int k = 0; k < CH; k++) {
        int idx = c0 + k;
        if (idx < NBIN) { buf[idx] = run; run += v[k]; }
    }
}

// ---------------- k_hist: per-block bin histogram H[blk][bin] | W transposes --------
__global__ __launch_bounds__(256) void k_hist(const float* __restrict__ W,
                                              const float* __restrict__ Wfc,
                                              unsigned short* __restrict__ WhT,
                                              unsigned short* __restrict__ WlT,
                                              unsigned short* __restrict__ WT,
                                              const int* __restrict__ edst,
                                              unsigned* __restrict__ H, int e, int ns) {
    __shared__ unsigned lh[NBIN];
    int b = blockIdx.x, t = threadIdx.x;
    if (b < ns) {
        for (int k = t; k < NBIN; k += 256) lh[k] = 0u;
        __syncthreads();
        int e0 = b * SBLK;
        int lim = e - e0; if (lim > SBLK) lim = SBLK;
        for (int k = t; k < lim; k += 256) atomicAdd(&lh[edst[e0 + k] >> 6], 1u);
        __syncthreads();
        for (int k = t; k < NBIN; k += 256) H[(size_t)b * NBIN + k] = lh[k];
    } else {
        int gid = (b - ns) * 256 + t;
        int stride = ((int)gridDim.x - ns) * 256;
        for (int i = gid; i < 128 * 128; i += stride) {
            int c = i >> 7, k = i & 127;
            float v = W[k * 128 + c];
            unsigned hi = bf16rn(v);
            WhT[c * 128 + k] = (unsigned short)hi;
            WlT[c * 128 + k] = (unsigned short)bf16rn(v - __uint_as_float(hi << 16));
        }
        for (int i = gid; i < 48 * 128; i += stride) {
            int nc = i >> 7, k = i & 127;
            WT[nc * 128 + k] = (unsigned short)((nc < 40) ? bf16rn(Wfc[k * 40 + nc]) : 0u);
        }
    }
}

// ---------------- k_scan: per-bin exclusive scan over blocks (in place) + tot -------
__global__ __launch_bounds__(256) void k_scan(unsigned* __restrict__ H,
                                              unsigned* __restrict__ tot, int ns) {
    int bin = blockIdx.x * 4 + (threadIdx.x >> 6);
    int lane = threadIdx.x & 63;
    if (bin >= NBIN) return;  // wave-uniform
    unsigned run = 0;
    for (int base = 0; base < ns; base += 64) {
        int idx = base + lane;
        unsigned v = (idx < ns) ? H[(size_t)idx * NBIN + bin] : 0u;
        unsigned inc = v;
#pragma unroll
        for (int off = 1; off < 64; off <<= 1) {
            unsigned tmp = __shfl_up(inc, off);
            if (lane >= off) inc += tmp;
        }
        if (idx < ns) H[(size_t)idx * NBIN + bin] = run + inc - v;
        run += __shfl(inc, 63);
    }
    if (lane == 0) tot[bin] = run;
}

// ---------------- k_binscan: 1 wave, exclusive scan of tot -> bstart[0..NBIN] -------
__global__ void k_binscan(const unsigned* __restrict__ tot, unsigned* __restrict__ bstart) {
    int lane = threadIdx.x;  // 64 threads
    const int CH = (NBIN + 63) / 64;
    unsigned v[CH];
    unsigned s = 0;
    int c0 = lane * CH;
#pragma unroll
    for (int k = 0; k < CH; k++) {
        int idx = c0 + k;
        v[k] = (idx < NBIN) ? tot[idx] : 0u;
        s += v[k];
    }
    unsigned inc = s;
#pragma unroll
    for (int off = 1; off < 64; off <<= 1) {
        unsigned tmp = __shfl_up(inc, off);
        if (lane >= off) inc += tmp;
    }
    unsigned run = inc - s;
#pragma unroll
    for (int k = 0; k < CH; k++) {
        int idx = c0 + k;
        if (idx < NBIN) { bstart[idx] = run; run += v[k]; }
    }
    if (lane == 63) bstart[NBIN] = run;  // grand total
}

// ---------------- k_sort: counting-sort edges by bin (no global atomics) | gemm1 ----
// rec = (bin<<22) | (dstlow<<16) | src
__global__ __launch_bounds__(256, 4) void k_sort(const float* __restrict__ x,
                                                 const unsigned short* __restrict__ WhT,
                                                 const unsigned short* __restrict__ WlT,
                                                 unsigned short* __restrict__ hbs,
                                                 const int* __restrict__ esrc,
                                                 const int* __restrict__ edst,
                                                 const unsigned* __restrict__ H,
                                                 const unsigned* __restrict__ bstart,
                                                 unsigned* __restrict__ recs,
                                                 int n, int e, int ns) {
    __shared__ unsigned bufA[NBIN];  // rank cursors
    __shared__ unsigned bufB[NBIN];  // global chunk base for this block
    __shared__ unsigned bufC[NBIN];  // local hist -> local exclusive start
    __shared__ unsigned sbuf[SBLK];
    int b = blockIdx.x, t = threadIdx.x;

    if (b < ns) {
        int e0 = b * SBLK;
        int myE = e - e0; if (myE > SBLK) myE = SBLK;
        for (int k = t; k < NBIN; k += 256) { bufC[k] = 0u; bufA[k] = 0u; }
        __syncthreads();
        for (int k = t; k < myE; k += 256) atomicAdd(&bufC[edst[e0 + k] >> 6], 1u);
        for (int bin = t; bin < NBIN; bin += 256)
            bufB[bin] = bstart[bin] + H[(size_t)b * NBIN + bin];
        __syncthreads();
        if (t < 64) wave_scan_excl_lds(bufC, t);  // exactly wave 0, full exec
        __syncthreads();
        for (int k = t; k < myE; k += 256) {
            int d = edst[e0 + k];
            int s = esrc[e0 + k];
            int bin = d >> 6;
            unsigned lr = atomicAdd(&bufA[bin], 1u);
            sbuf[bufC[bin] + lr] =
                ((unsigned)bin << 22) | ((unsigned)(d & 63) << 16) | (unsigned)s;
        }
        __syncthreads();
        for (int j = t; j < myE; j += 256) {
            unsigned rec = sbuf[j];
            unsigned bin = rec >> 22;
            recs[bufB[bin] + (unsigned)j - bufC[bin]] = rec;
        }
    } else {
        // ---- gemm1: h = x @ W_conv via 16x16x32 bf16 MFMA, hi/lo split ----
        int r0 = (b - ns) * 128;
        int wid = t >> 6, lane = t & 63;
        int mrow = lane & 15, quad = lane >> 4;
        int rb = r0 + wid * 32;

        f32x4 acc[2][8];
#pragma unroll
        for (int m = 0; m < 2; m++)
#pragma unroll
            for (int nn = 0; nn < 8; nn++) acc[m][nn] = (f32x4){0.f, 0.f, 0.f, 0.f};

#pragma unroll
        for (int ks = 0; ks < 4; ks++) {
            short8 Ah[2], Al[2];
#pragma unroll
            for (int m = 0; m < 2; m++) {
                int r = rb + m * 16 + mrow;
                if (r >= n) r = n - 1;
                const float* xp = &x[(long)r * C_DIM + ks * 32 + quad * 8];
                float4 va = *(const float4*)xp;
                float4 vb = *(const float4*)(xp + 4);
                float xv[8] = {va.x, va.y, va.z, va.w, vb.x, vb.y, vb.z, vb.w};
#pragma unroll
                for (int e8 = 0; e8 < 8; e8++) {
                    unsigned hi = bf16rn(xv[e8]);
                    Ah[m][e8] = (short)hi;
                    Al[m][e8] = (short)bf16rn(xv[e8] - __uint_as_float(hi << 16));
                }
            }
#pragma unroll
            for (int nn = 0; nn < 8; nn++) {
                int wof = (nn * 16 + mrow) * 128 + ks * 32 + quad * 8;
                short8 Bh = *(const short8*)&WhT[wof];
                short8 Bl = *(const short8*)&WlT[wof];
#pragma unroll
                for (int m = 0; m < 2; m++) {
                    acc[m][nn] = __builtin_amdgcn_mfma_f32_16x16x32_bf16(Ah[m], Bh, acc[m][nn], 0, 0, 0);
                    acc[m][nn] = __builtin_amdgcn_mfma_f32_16x16x32_bf16(Al[m], Bh, acc[m][nn], 0, 0, 0);
                    acc[m][nn] = __builtin_amdgcn_mfma_f32_16x16x32_bf16(Ah[m], Bl, acc[m][nn], 0, 0, 0);
                }
            }
        }
#pragma unroll
        for (int m = 0; m < 2; m++)
#pragma unroll
            for (int nn = 0; nn < 8; nn++) {
                int c = nn * 16 + mrow;
#pragma unroll
                for (int reg = 0; reg < 4; reg++) {
                    int r = rb + m * 16 + quad * 4 + reg;
                    if (r < n) hbs[(long)r * 128 + c] = (unsigned short)bf16rn(acc[m][nn][reg]);
                }
            }
    }
}

// ---------------- k_csr: per-bin sort by node -> CSR + rowptr + hb2 = dinv*h --------
__global__ __launch_bounds__(256) void k_csr(const unsigned* __restrict__ recs,
                                             const unsigned* __restrict__ bstart,
                                             const unsigned* __restrict__ hb,
                                             unsigned* __restrict__ hb2,
                                             unsigned short* __restrict__ csr,
                                             unsigned* __restrict__ rowptr, int n) {
    __shared__ unsigned nh[64], nstart[64], cur[64];
    __shared__ float dinvl[64];
    __shared__ unsigned short sl[4096];
    int bin = blockIdx.x, t = threadIdx.x;
    unsigned s0 = bstart[bin];
    unsigned cn = bstart[bin + 1] - s0;
    if (t < 64) { nh[t] = 0u; cur[t] = 0u; }
    __syncthreads();
    for (unsigned k = t; k < cn; k += 256) atomicAdd(&nh[(recs[s0 + k] >> 16) & 63u], 1u);
    __syncthreads();
    if (t < 64) {  // exactly wave 0, full exec
        unsigned v = nh[t];
        unsigned inc = v;
#pragma unroll
        for (int off = 1; off < 64; off <<= 1) {
            unsigned tmp = __shfl_up(inc, off);
            if (t >= off) inc += tmp;
        }
        unsigned excl = inc - v;
        nstart[t] = excl;
        rowptr[bin * 64 + t] = s0 + excl;
        dinvl[t] = rsqrtf((float)v + 1.0f);
    }
    __syncthreads();
    for (unsigned k = t; k < cn; k += 256) {
        unsigned rec = recs[s0 + k];
        unsigned nd = (rec >> 16) & 63u;
        unsigned r = atomicAdd(&cur[nd], 1u);
        unsigned idx = nstart[nd] + r;
        if (idx < 4096) sl[idx] = (unsigned short)(rec & 0xFFFFu);
        else csr[s0 + idx] = (unsigned short)(rec & 0xFFFFu);  // rare big-bin overflow: direct
    }
    __syncthreads();
    for (unsigned k = t; k < cn && k < 4096; k += 256) csr[s0 + k] = sl[k];
    // hb2 = dinv * h for this bin's 64 rows (fused d0)
    for (int idx = t; idx < 1024; idx += 256) {
        int row = idx >> 4;
        int node = bin * 64 + row;
        if (node < n) {
            float di = dinvl[row];
            uint4 u = ((const uint4*)hb)[(size_t)node * 16 + (idx & 15)];
            uint4 o;
            o.x = pack_bf16(di * blo(u.x), di * bhi(u.x));
            o.y = pack_bf16(di * blo(u.y), di * bhi(u.y));
            o.z = pack_bf16(di * blo(u.z), di * bhi(u.z));
            o.w = pack_bf16(di * blo(u.w), di * bhi(u.w));
            ((uint4*)hb2)[(size_t)node * 16 + (idx & 15)] = o;
        }
    }
}

// ---------------- fused aggregate + bias + relu*x + LN + residual (CSR) --------
// One wave per node. Slot table = first 64 srcs (contiguous csr read); slots >=64
// (astronomically rare) read csr directly — branch is wave-uniform per unrolled
// step. Gather loop WAVE-UNIFORM (round-1 lesson).
__global__ __launch_bounds__(256) void aggregate(const unsigned* __restrict__ hb2,
                                                 const float* __restrict__ x,
                                                 const unsigned short* __restrict__ csr,
                                                 const unsigned* __restrict__ rowptr,
                                                 const float* __restrict__ bconv,
                                                 const float* __restrict__ gamma,
                                                 const float* __restrict__ beta,
                                                 unsigned* __restrict__ zb, int n) {
    int wid = (blockIdx.x * blockDim.x + threadIdx.x) >> 6;
    if (wid >= n) return;  // wave-uniform
    int lane = threadIdx.x & 63;
    int sub = lane & 15, grp = lane >> 4;
    int i = wid;

    unsigned rs = rowptr[i];
    unsigned re = rowptr[i + 1];
    int deg = (int)(re - rs);
    float di = rsqrtf((float)deg + 1.0f);

    // hoist independent loads
    uint4 us = *(const uint4*)(hb2 + (long)i * 64 + sub * 4);
    float4 xa = *(const float4*)&x[(long)i * C_DIM + sub * 8];
    float4 xb = *(const float4*)&x[(long)i * C_DIM + sub * 8 + 4];
    int s_all = (int)csr[rs + lane];  // over-reads past deg are padded/harmless

    float wself = (grp == 0) ? 1.f : 0.f;  // self term = hb2[i] (di applied after reduce)
    float acc[8];
    acc[0] = wself * blo(us.x); acc[1] = wself * bhi(us.x);
    acc[2] = wself * blo(us.y); acc[3] = wself * bhi(us.y);
    acc[4] = wself * blo(us.z); acc[5] = wself * bhi(us.z);
    acc[6] = wself * blo(us.w); acc[7] = wself * bhi(us.w);

    int nIt = (deg + 15) >> 4;  // UNIFORM trip count; 16 slots (4 per grp) per iter
    for (int it = 0; it < nIt; ++it) {
        int ss[4];
        float ww[4];
#pragma unroll
        for (int qq = 0; qq < 4; qq++) {
            int base = it * 16 + qq * 4;  // multiple of 4 -> (base>=64) uniform across wave
            int tq = base + grp;
            int sq;
            if (base >= 64) sq = (int)csr[rs + tq];  // rare fallback, wave-uniform branch
            else sq = __shfl(s_all, tq);             // full-exec bpermute
            float wq = 1.f;
            if (tq >= deg) { wq = 0.f; sq = i; }  // predicate AFTER shuffle
            ss[qq] = sq;
            ww[qq] = wq;
        }
        uint4 u[4];
#pragma unroll
        for (int qq = 0; qq < 4; qq++) u[qq] = *(const uint4*)(hb2 + (long)ss[qq] * 64 + sub * 4);
#pragma unroll
        for (int qq = 0; qq < 4; qq++) {
            float w = ww[qq];
            acc[0] += w * blo(u[qq].x); acc[1] += w * bhi(u[qq].x);
            acc[2] += w * blo(u[qq].y); acc[3] += w * bhi(u[qq].y);
            acc[4] += w * blo(u[qq].z); acc[5] += w * bhi(u[qq].z);
            acc[6] += w * blo(u[qq].w); acc[7] += w * bhi(u[qq].w);
        }
    }

#pragma unroll
    for (int j = 0; j < 8; j++) {
        acc[j] += __shfl_xor(acc[j], 16);
        acc[j] += __shfl_xor(acc[j], 32);
    }

    float4 bca = *(const float4*)&bconv[sub * 8];
    float4 bcb = *(const float4*)&bconv[sub * 8 + 4];
    float a[8], xv[8];
    xv[0] = xa.x; xv[1] = xa.y; xv[2] = xa.z; xv[3] = xa.w;
    xv[4] = xb.x; xv[5] = xb.y; xv[6] = xb.z; xv[7] = xb.w;
    float bc[8] = {bca.x, bca.y, bca.z, bca.w, bcb.x, bcb.y, bcb.z, bcb.w};
#pragma unroll
    for (int j = 0; j < 8; j++) a[j] = fmaxf(acc[j] * di + bc[j], 0.f) * xv[j];

    float s = a[0] + a[1] + a[2] + a[3] + a[4] + a[5] + a[6] + a[7];
#pragma unroll
    for (int off = 1; off < 16; off <<= 1) s += __shfl_xor(s, off);
    float mu = s * (1.0f / 128.0f);
    float d[8], v = 0.f;
#pragma unroll
    for (int j = 0; j < 8; j++) { d[j] = a[j] - mu; v += d[j] * d[j]; }
#pragma unroll
    for (int off = 1; off < 16; off <<= 1) v += __shfl_xor(v, off);
    float inv = rsqrtf(v * (1.0f / 128.0f) + EPS);

    if (grp == 0) {
        float4 ga = *(const float4*)&gamma[sub * 8];
        float4 gb = *(const float4*)&gamma[sub * 8 + 4];
        float4 ba = *(const float4*)&beta[sub * 8];
        float4 bb = *(const float4*)&beta[sub * 8 + 4];
        float g[8] = {ga.x, ga.y, ga.z, ga.w, gb.x, gb.y, gb.z, gb.w};
        float be[8] = {ba.x, ba.y, ba.z, ba.w, bb.x, bb.y, bb.z, bb.w};
        float o[8];
#pragma unroll
        for (int j = 0; j < 8; j++) o[j] = d[j] * inv * g[j] + be[j] + xv[j];
        uint4 p;
        p.x = pack_bf16(o[0], o[1]);
        p.y = pack_bf16(o[2], o[3]);
        p.z = pack_bf16(o[4], o[5]);
        p.w = pack_bf16(o[6], o[7]);
        *(uint4*)(zb + (long)i * 64 + sub * 4) = p;
    }
}

// ---------------- GEMM2: out = z @ W_fc + b_fc via bf16 MFMA, no LDS ----------------
__global__ __launch_bounds__(256) void gemm2(const unsigned short* __restrict__ zb,
                                             const unsigned short* __restrict__ WT,
                                             const float* __restrict__ bfc,
                                             float* __restrict__ out, int n) {
    int t = threadIdx.x;
    int w = t >> 6, lane = t & 63;
    int r0 = blockIdx.x * 64 + w * 16;
    if (r0 >= n) return;  // wave-uniform
    int mrow = lane & 15;
    int quad = lane >> 4;
    f32x4 acc[3];
#pragma unroll
    for (int nt = 0; nt < 3; nt++) acc[nt] = (f32x4){0.f, 0.f, 0.f, 0.f};
#pragma unroll
    for (int ks = 0; ks < 4; ks++) {
        int r = r0 + mrow;
        if (r >= n) r = n - 1;  // clamp (stores are guarded)
        short8 A = *(const short8*)&zb[(long)r * 128 + ks * 32 + quad * 8];
        short8 B[3];
#pragma unroll
        for (int nt = 0; nt < 3; nt++)
            B[nt] = *(const short8*)&WT[(nt * 16 + mrow) * 128 + ks * 32 + quad * 8];
#pragma unroll
        for (int nt = 0; nt < 3; nt++)
            acc[nt] = __builtin_amdgcn_mfma_f32_16x16x32_bf16(A, B[nt], acc[nt], 0, 0, 0);
    }
#pragma unroll
    for (int nt = 0; nt < 3; nt++) {
        int c = nt * 16 + mrow;
        if (c < 40) {
            float bias = bfc[c];
#pragma unroll
            for (int reg = 0; reg < 4; reg++) {
                int r = r0 + quad * 4 + reg;
                if (r < n) out[(long)r * 40 + c] = acc[nt][reg] + bias;
            }
        }
    }
}

extern "C" void kernel_launch(void* const* d_in, const int* in_sizes, int n_in,
                              void* d_out, int out_size, void* d_ws, size_t ws_size,
                              hipStream_t stream) {
    const float* x     = (const float*)d_in[0];
    const int*   ei    = (const int*)d_in[1];
    const float* Wc    = (const float*)d_in[2];
    const float* bc    = (const float*)d_in[3];
    const float* gamma = (const float*)d_in[4];
    const float* beta  = (const float*)d_in[5];
    const float* Wfc   = (const float*)d_in[6];
    const float* bfc   = (const float*)d_in[7];
    float* out = (float*)d_out;

    int N = in_sizes[0] / C_DIM;
    int E = in_sizes[1] / 2;
    const int* esrc = ei;
    const int* edst = ei + E;
    int ns = (E + SBLK - 1) / SBLK;  // 313 sort blocks
    int g1 = (N + 127) / 128;        // gemm1 blocks

    char* p = (char*)d_ws;
    auto carve = [&](size_t bytes) {
        void* q = (void*)p;
        p += (bytes + 255) & ~(size_t)255;
        return q;
    };
    unsigned* hb         = (unsigned*)carve((size_t)N * 64 * 4);        // h bf16 pairs (reused as zb)
    unsigned* hb2        = (unsigned*)carve((size_t)N * 64 * 4);        // dinv-scaled h
    unsigned short* WT   = (unsigned short*)carve(48 * 128 * 2);
    unsigned short* WhT  = (unsigned short*)carve(128 * 128 * 2);
    unsigned short* WlT  = (unsigned short*)carve(128 * 128 * 2);
    unsigned* H          = (unsigned*)carve((size_t)ns * NBIN * 4);     // hist [blk][bin]
    unsigned* tot        = (unsigned*)carve((size_t)NBIN * 4);
    unsigned* bstart     = (unsigned*)carve((size_t)(NBIN + 1) * 4);
    unsigned* recs       = (unsigned*)carve((size_t)E * 4);             // bin-sorted recs
    unsigned* rowptr     = (unsigned*)carve((size_t)(NBIN * 64 + 1) * 4);
    unsigned short* csr  = (unsigned short*)carve((size_t)E * 2 + 256); // node-sorted srcs (+pad)

    unsigned* zb = hb;  // alias: hb dead after k_csr

    k_hist<<<ns + 64, 256, 0, stream>>>(Wc, Wfc, WhT, WlT, WT, edst, H, E, ns);
    k_scan<<<NBIN / 4, 256, 0, stream>>>(H, tot, ns);
    k_binscan<<<1, 64, 0, stream>>>(tot, bstart);
    k_sort<<<ns + g1, 256, 0, stream>>>(x, WhT, WlT, (unsigned short*)hb, esrc, edst,
                                        H, bstart, recs, N, E, ns);
    k_csr<<<NBIN, 256, 0, stream>>>(recs, bstart, hb, hb2, csr, rowptr, N);
    aggregate<<<((size_t)N * 64 + 255) / 256, 256, 0, stream>>>(
        hb2, x, csr, rowptr, bc, gamma, beta, zb, N);
    gemm2<<<(N + 63) / 64, 256, 0, stream>>>((const unsigned short*)zb, WT, bfc, out, N);
}